// Round 1
// baseline (201.606 us; speedup 1.0000x reference)
//
#include <hip/hip_runtime.h>
#include <math.h>

// Problem constants (match reference)
constexpr int BN = 128;
constexpr int FH = 26, FW = 26;
constexpr int T  = 50;
constexpr int A  = 5;
constexpr int NC = 20;
constexpr int K  = FH * FW;     // 676
constexpr int KA = K * A;       // 3380
constexpr int CH = A * (5 + NC); // 125

constexpr float IGNORE_THRESH = 0.75f;
constexpr float OBJ_SCALE = 5.0f;
constexpr float NOOBJ_SCALE = 1.0f;

__constant__ float ANCW[A] = {1.3221f, 3.19275f, 5.05587f, 9.47112f, 11.2364f};
__constant__ float ANCH[A] = {1.73145f, 4.00944f, 8.09892f, 4.84053f, 10.0071f};

__device__ __forceinline__ float sigmoidf(float x) {
    return 1.0f / (1.0f + expf(-x));
}

__global__ void zero_out_kernel(float* out) {
    if (threadIdx.x == 0 && blockIdx.x == 0) out[0] = 0.0f;
}

__global__ __launch_bounds__(256) void yolo_loss_kernel(
        const float* __restrict__ outputs,   // (B, 125, 26, 26)
        const float* __restrict__ targets,   // (B, 50, 5)
        float* __restrict__ out) {           // scalar accumulator
    __shared__ float g_x1[T], g_y1[T], g_x2[T], g_y2[T], g_area[T];
    __shared__ float tb0[T], tb1[T], tb2[T], tb3[T];
    __shared__ int   tcls[T];
    __shared__ int   tvalid[T];
    __shared__ int   winner[KA];   // last valid t assigned to slot, else -1
    __shared__ float miou[KA];     // max pred-IoU per slot
    __shared__ int   pos_any;
    __shared__ float red[4];

    const int b   = blockIdx.x;
    const int tid = threadIdx.x;
    const float* ob = outputs + (size_t)b * CH * K;

    for (int s = tid; s < KA; s += blockDim.x) winner[s] = -1;
    if (tid == 0) pos_any = 0;

    // ---- Phase 1: per-GT decode + anchor assignment (threads 0..T-1) ----
    if (tid < T) {
        const float* g = targets + ((size_t)b * T + tid) * 5;
        float rx1 = g[0], ry1 = g[1], rx2 = g[2], ry2 = g[3];
        int valid = (rx1 + ry1 + rx2 + ry2) > 0.0f;
        float x1 = rx1 * FW, y1 = ry1 * FH, x2 = rx2 * FW, y2 = ry2 * FH;
        g_x1[tid] = x1; g_y1[tid] = y1; g_x2[tid] = x2; g_y2[tid] = y2;
        float w = x2 - x1, h = y2 - y1;
        g_area[tid] = w * h;
        tvalid[tid] = valid;

        float cxf = 0.5f * (x1 + x2), cyf = 0.5f * (y1 + y2);
        int cx = (int)floorf(cxf); cx = min(max(cx, 0), FW - 1);
        int cy = (int)floorf(cyf); cy = min(max(cy, 0), FH - 1);
        int cell = cy * FW + cx;

        // argmax over anchors of IoU(anchor-box @ cell-center, gt) — first max wins
        float acx = (float)cx + 0.5f, acy = (float)cy + 0.5f;
        float best = -1.0f; int ai = 0;
        for (int a = 0; a < A; ++a) {
            float aw = ANCW[a], ah = ANCH[a];
            float ax1 = acx - 0.5f * aw, ay1 = acy - 0.5f * ah;
            float ax2 = acx + 0.5f * aw, ay2 = acy + 0.5f * ah;
            float xi1 = fmaxf(ax1, x1), yi1 = fmaxf(ay1, y1);
            float xi2 = fminf(ax2, x2), yi2 = fminf(ay2, y2);
            float inter = fmaxf(xi2 - xi1, 0.0f) * fmaxf(yi2 - yi1, 0.0f);
            float iou = inter / (aw * ah + w * h - inter);
            if (iou > best) { best = iou; ai = a; }
        }

        tb0[tid] = cxf - (float)cx;
        tb1[tid] = cyf - (float)cy;
        tb2[tid] = w / ANCW[ai];
        tb3[tid] = h / ANCH[ai];
        tcls[tid] = (int)g[4];

        if (valid) {
            int slot = ai * K + cell;
            atomicMax(&winner[slot], tid);  // scan overwrite => last valid t wins
        }
    }
    __syncthreads();

    // ---- Phase 2: per-slot max pred-IoU over GT boxes ----
    int any_local = 0;
    for (int s = tid; s < KA; s += blockDim.x) {
        int a = s / K, k = s - a * K;
        int y = k / FW, x = k - y * FW;
        float o0 = ob[(a * 25 + 0) * K + k];
        float o1 = ob[(a * 25 + 1) * K + k];
        float o2 = ob[(a * 25 + 2) * K + k];
        float o3 = ob[(a * 25 + 3) * K + k];
        float px = (float)x + sigmoidf(o0);
        float py = (float)y + sigmoidf(o1);
        float pw = ANCW[a] * expf(o2);
        float ph = ANCH[a] * expf(o3);
        float px1 = px - 0.5f * pw, px2 = px + 0.5f * pw;
        float py1 = py - 0.5f * ph, py2 = py + 0.5f * ph;
        float parea = pw * ph;
        float m = -1.0f;
        for (int t = 0; t < T; ++t) {
            if (!tvalid[t]) continue;
            float xi1 = fmaxf(px1, g_x1[t]), yi1 = fmaxf(py1, g_y1[t]);
            float xi2 = fminf(px2, g_x2[t]), yi2 = fminf(py2, g_y2[t]);
            float inter = fmaxf(xi2 - xi1, 0.0f) * fmaxf(yi2 - yi1, 0.0f);
            float iou = inter / (parea + g_area[t] - inter);
            m = fmaxf(m, iou);
        }
        miou[s] = m;
        if (m > IGNORE_THRESH) any_local = 1;
    }
    if (any_local) pos_any = 1;   // all writers store the same value
    __syncthreads();
    const int pany = pos_any;

    // ---- Phase 3: loss accumulation ----
    float acc = 0.0f;
    for (int s = tid; s < KA; s += blockDim.x) {
        int a = s / K, k = s - a * K;
        float o4 = ob[(a * 25 + 4) * K + k];
        float conf = sigmoidf(o4);
        int w = winner[s];
        float m = miou[s];
        float im, it;
        if (w >= 0) { im = OBJ_SCALE; it = m; }
        else        { im = (pany && m >= IGNORE_THRESH) ? 0.0f : NOOBJ_SCALE; it = 0.0f; }
        float d = (conf - it) * im;
        acc += 0.5f * d * d;

        if (w >= 0) {
            // box loss
            float o0 = ob[(a * 25 + 0) * K + k];
            float o1 = ob[(a * 25 + 1) * K + k];
            float o2 = ob[(a * 25 + 2) * K + k];
            float o3 = ob[(a * 25 + 3) * K + k];
            float d0 = sigmoidf(o0) - tb0[w];
            float d1 = sigmoidf(o1) - tb1[w];
            float d2 = expf(o2)     - tb2[w];
            float d3 = expf(o3)     - tb3[w];
            acc += 0.5f * (d0 * d0 + d1 * d1 + d2 * d2 + d3 * d3);

            // class cross-entropy: lse - score[target]
            float mx = -1e30f;
            for (int c = 0; c < NC; ++c)
                mx = fmaxf(mx, ob[(a * 25 + 5 + c) * K + k]);
            float se = 0.0f;
            for (int c = 0; c < NC; ++c)
                se += expf(ob[(a * 25 + 5 + c) * K + k] - mx);
            float tsc = ob[(a * 25 + 5 + tcls[w]) * K + k];
            acc += (logf(se) + mx) - tsc;
        }
    }

    // ---- block reduce (4 waves of 64) ----
    for (int off = 32; off > 0; off >>= 1)
        acc += __shfl_down(acc, off);
    int lane = tid & 63, wv = tid >> 6;
    if (lane == 0) red[wv] = acc;
    __syncthreads();
    if (tid == 0) {
        float s = red[0] + red[1] + red[2] + red[3];
        atomicAdd(out, s * (1.0f / (float)BN));
    }
}

extern "C" void kernel_launch(void* const* d_in, const int* in_sizes, int n_in,
                              void* d_out, int out_size, void* d_ws, size_t ws_size,
                              hipStream_t stream) {
    const float* outputs = (const float*)d_in[0];
    const float* targets = (const float*)d_in[1];
    float* out = (float*)d_out;

    // d_out is poisoned (0xAA) before every timed launch — zero it first.
    zero_out_kernel<<<1, 1, 0, stream>>>(out);
    yolo_loss_kernel<<<BN, 256, 0, stream>>>(outputs, targets, out);
}

// Round 2
// 110.644 us; speedup vs baseline: 1.8221x; 1.8221x over previous
//
#include <hip/hip_runtime.h>
#include <math.h>

// Problem constants (match reference)
constexpr int BN = 128;
constexpr int FH = 26, FW = 26;
constexpr int T  = 50;
constexpr int A  = 5;
constexpr int NC = 20;
constexpr int K  = FH * FW;      // 676
constexpr int KA = K * A;        // 3380
constexpr int CH = A * (5 + NC); // 125
constexpr int REC = 12;          // floats per GT record

constexpr float IGNORE_THRESH = 0.75f;
constexpr float OBJ_SCALE = 5.0f;
// NOOBJ_SCALE = 1.0 (folded into the math below)

constexpr int CHUNKS = (KA + 255) / 256;   // 14 blocks of 256 per batch

__constant__ float ANCW[A] = {1.3221f, 3.19275f, 5.05587f, 9.47112f, 11.2364f};
__constant__ float ANCH[A] = {1.73145f, 4.00944f, 8.09892f, 4.84053f, 10.0071f};

__device__ __forceinline__ float sigmoidf(float x) {
    return 1.0f / (1.0f + expf(-x));
}

// ---------------------------------------------------------------------------
// K0: per-GT decode. One thread per (b, t). Also zero-inits the accumulators.
// Record layout (12 floats): x1,y1,x2,y2,area,valid, tb0,tb1,tb2,tb3, cls, slot
// slot = assigned a*K+cell if valid else -1 (winner resolution deferred to K1:
// each slot scans the 50-record list ascending; last valid match wins = scan).
// ---------------------------------------------------------------------------
__global__ __launch_bounds__(256) void yolo_prep(
        const float* __restrict__ targets, float* __restrict__ gtrec,
        int* __restrict__ pos_any, float* __restrict__ s_masked,
        float* __restrict__ out) {
    int i = blockIdx.x * 256 + threadIdx.x;
    if (i == 0) out[0] = 0.0f;
    if (i < BN) { pos_any[i] = 0; s_masked[i] = 0.0f; }
    if (i >= BN * T) return;

    const float* g = targets + (size_t)i * 5;
    float rx1 = g[0], ry1 = g[1], rx2 = g[2], ry2 = g[3];
    bool valid = (rx1 + ry1 + rx2 + ry2) > 0.0f;
    float x1 = rx1 * FW, y1 = ry1 * FH, x2 = rx2 * FW, y2 = ry2 * FH;
    float w = x2 - x1, h = y2 - y1;

    float cxf = 0.5f * (x1 + x2), cyf = 0.5f * (y1 + y2);
    int cx = (int)floorf(cxf); cx = min(max(cx, 0), FW - 1);
    int cy = (int)floorf(cyf); cy = min(max(cy, 0), FH - 1);
    int cell = cy * FW + cx;

    // argmax over anchors of IoU(anchor@cell-center, gt) — first max wins
    float acx = (float)cx + 0.5f, acy = (float)cy + 0.5f;
    float best = -1.0f; int ai = 0;
    for (int a = 0; a < A; ++a) {
        float aw = ANCW[a], ah = ANCH[a];
        float xi1 = fmaxf(acx - 0.5f * aw, x1), yi1 = fmaxf(acy - 0.5f * ah, y1);
        float xi2 = fminf(acx + 0.5f * aw, x2), yi2 = fminf(acy + 0.5f * ah, y2);
        float inter = fmaxf(xi2 - xi1, 0.0f) * fmaxf(yi2 - yi1, 0.0f);
        float iou = inter / (aw * ah + w * h - inter);
        if (iou > best) { best = iou; ai = a; }
    }

    float* r = gtrec + (size_t)i * REC;
    r[0] = x1; r[1] = y1; r[2] = x2; r[3] = y2;
    r[4] = w * h;
    r[5] = valid ? 1.0f : 0.0f;
    r[6] = cxf - (float)cx;
    r[7] = cyf - (float)cy;
    r[8] = w / ANCW[ai];
    r[9] = h / ANCH[ai];
    r[10] = g[4];
    r[11] = valid ? (float)(ai * K + cell) : -1.0f;
}

// ---------------------------------------------------------------------------
// K1: main pass. One thread per (batch, slot). grid = (CHUNKS, BN).
// Accumulates total loss assuming pos_any handling deferred: noobj conf term
// added unconditionally for unassigned slots; the subset with m>=thresh is
// also summed into s_masked[b] for later subtraction if pos_any[b].
// ---------------------------------------------------------------------------
__global__ __launch_bounds__(256) void yolo_main(
        const float* __restrict__ outputs, const float* __restrict__ gtrec,
        int* __restrict__ pos_any, float* __restrict__ s_masked,
        float* __restrict__ out) {
    __shared__ float ld[T * REC];
    __shared__ float redl[4], redm[4];
    __shared__ int   reda[4];

    const int b   = blockIdx.y;
    const int tid = threadIdx.x;
    for (int i = tid; i < T * REC; i += 256) ld[i] = gtrec[(size_t)b * T * REC + i];
    __syncthreads();

    const int s = blockIdx.x * 256 + tid;
    float loss = 0.0f, masked = 0.0f;
    int any = 0;

    if (s < KA) {
        const int a = s / K, k = s - a * K;
        const int y = k / FW, x = k - y * FW;
        const float* ob = outputs + (size_t)b * CH * K;

        float o0 = ob[(a * 25 + 0) * K + k];
        float o1 = ob[(a * 25 + 1) * K + k];
        float o2 = ob[(a * 25 + 2) * K + k];
        float o3 = ob[(a * 25 + 3) * K + k];
        float o4 = ob[(a * 25 + 4) * K + k];

        float s0 = sigmoidf(o0), s1 = sigmoidf(o1);
        float e2 = expf(o2),     e3 = expf(o3);
        float px = (float)x + s0, py = (float)y + s1;
        float pw = ANCW[a] * e2,  ph = ANCH[a] * e3;
        float px1 = px - 0.5f * pw, px2 = px + 0.5f * pw;
        float py1 = py - 0.5f * ph, py2 = py + 0.5f * ph;
        float parea = pw * ph;

        float m = -1.0f;
        int w = -1;
        for (int t = 0; t < T; ++t) {
            const float* r = &ld[t * REC];
            if (r[5] != 0.0f) {
                float xi1 = fmaxf(px1, r[0]), yi1 = fmaxf(py1, r[1]);
                float xi2 = fminf(px2, r[2]), yi2 = fminf(py2, r[3]);
                float inter = fmaxf(xi2 - xi1, 0.0f) * fmaxf(yi2 - yi1, 0.0f);
                float iou = inter / (parea + r[4] - inter);
                m = fmaxf(m, iou);
                if ((int)r[11] == s) w = t;   // ascending t => last valid wins
            }
        }
        any = (m > IGNORE_THRESH) ? 1 : 0;

        float conf = sigmoidf(o4);
        if (w >= 0) {
            // assigned: conf MSE at OBJ scale + box MSE + class CE
            float d = (conf - m) * OBJ_SCALE;
            loss += 0.5f * d * d;
            const float* r = &ld[w * REC];
            float d0 = s0 - r[6], d1 = s1 - r[7];
            float d2 = e2 - r[8], d3 = e3 - r[9];
            loss += 0.5f * (d0 * d0 + d1 * d1 + d2 * d2 + d3 * d3);

            float mx = -1e30f;
            for (int c = 0; c < NC; ++c)
                mx = fmaxf(mx, ob[(a * 25 + 5 + c) * K + k]);
            float se = 0.0f;
            for (int c = 0; c < NC; ++c)
                se += expf(ob[(a * 25 + 5 + c) * K + k] - mx);
            int cls = (int)r[10];
            loss += (logf(se) + mx) - ob[(a * 25 + 5 + cls) * K + k];
        } else {
            // unassigned: noobj term (NOOBJ_SCALE=1); maybe cancelled later
            float term = 0.5f * conf * conf;
            loss += term;
            if (m >= IGNORE_THRESH) masked += term;
        }
    }

    // block reduce: loss, masked (float) and any (bool)
    for (int off = 32; off > 0; off >>= 1) {
        loss   += __shfl_down(loss, off);
        masked += __shfl_down(masked, off);
    }
    any = __any(any) ? 1 : 0;
    int lane = tid & 63, wv = tid >> 6;
    if (lane == 0) { redl[wv] = loss; redm[wv] = masked; reda[wv] = any; }
    __syncthreads();
    if (tid == 0) {
        float L = redl[0] + redl[1] + redl[2] + redl[3];
        float M = redm[0] + redm[1] + redm[2] + redm[3];
        int   An = reda[0] | reda[1] | reda[2] | reda[3];
        atomicAdd(out, L * (1.0f / (float)BN));
        if (M != 0.0f) atomicAdd(&s_masked[b], M);
        if (An) atomicOr(&pos_any[b], 1);
    }
}

// ---------------------------------------------------------------------------
// K2: apply the pos_any correction: out -= sum_b pany[b] * s_masked[b] / BN
// ---------------------------------------------------------------------------
__global__ __launch_bounds__(128) void yolo_fix(
        const int* __restrict__ pos_any, const float* __restrict__ s_masked,
        float* __restrict__ out) {
    __shared__ float red[2];
    int tid = threadIdx.x;
    float v = (tid < BN && pos_any[tid]) ? s_masked[tid] : 0.0f;
    for (int off = 32; off > 0; off >>= 1) v += __shfl_down(v, off);
    if ((tid & 63) == 0) red[tid >> 6] = v;
    __syncthreads();
    if (tid == 0) atomicAdd(out, -(red[0] + red[1]) * (1.0f / (float)BN));
}

extern "C" void kernel_launch(void* const* d_in, const int* in_sizes, int n_in,
                              void* d_out, int out_size, void* d_ws, size_t ws_size,
                              hipStream_t stream) {
    const float* outputs = (const float*)d_in[0];
    const float* targets = (const float*)d_in[1];
    float* out = (float*)d_out;

    // ws layout: gt records | pos_any | s_masked  (~308 KB total)
    float* gtrec    = (float*)d_ws;                       // BN*T*REC floats
    int*   pos_any  = (int*)((char*)d_ws + (size_t)BN * T * REC * 4);
    float* s_masked = (float*)((char*)pos_any + BN * sizeof(int));

    yolo_prep<<<(BN * T + 255) / 256, 256, 0, stream>>>(targets, gtrec, pos_any, s_masked, out);
    yolo_main<<<dim3(CHUNKS, BN), 256, 0, stream>>>(outputs, gtrec, pos_any, s_masked, out);
    yolo_fix<<<1, 128, 0, stream>>>(pos_any, s_masked, out);
}

// Round 3
// 93.002 us; speedup vs baseline: 2.1678x; 1.1897x over previous
//
#include <hip/hip_runtime.h>
#include <math.h>

// Problem constants (match reference)
constexpr int BN = 128;
constexpr int FH = 26, FW = 26;
constexpr int T  = 50;
constexpr int A  = 5;
constexpr int NC = 20;
constexpr int K  = FH * FW;      // 676
constexpr int KA = K * A;        // 3380
constexpr int CH = A * (5 + NC); // 125

constexpr float IGNORE_THRESH = 0.75f;
constexpr float OBJ_SCALE = 5.0f;
// NOOBJ_SCALE = 1.0 (folded into the math)

constexpr int CHUNKS = (KA + 255) / 256;   // 14 blocks of 256 per batch
constexpr int NPART  = BN * CHUNKS;        // 1792 partials

__constant__ float ANCW[A] = {1.3221f, 3.19275f, 5.05587f, 9.47112f, 11.2364f};
__constant__ float ANCH[A] = {1.73145f, 4.00944f, 8.09892f, 4.84053f, 10.0071f};

__device__ __forceinline__ float fast_sigmoid(float x) {
    return __builtin_amdgcn_rcpf(1.0f + __expf(-x));
}

// ---------------------------------------------------------------------------
// Main pass: grid (CHUNKS, BN), 256 threads. Each block:
//   1. threads 0..T-1 decode the 50 GT boxes of batch b into LDS (redundant
//      across the 14 chunks of a batch — trivial vs. a separate kernel+global
//      round trip).
//   2. one thread per slot s: decode pred, 50-iter IoU loop (rcp instead of
//      IEEE div; 2 packed DS broadcasts/iter; invalid GT encoded degenerate
//      so the loop is branch-free), winner = last t whose assigned slot == s
//      (== lax.scan overwrite semantics).
//   3. block-reduce {loss, masked-noobj-sum, any(m>thresh)} and plain-store
//      partials to ws — no atomics, no zero-init needed anywhere.
// pos_any correction is applied in the tiny fix kernel:
//      out = [ sum_b (L_b - pany_b * M_b) ] / BN
// ---------------------------------------------------------------------------
__global__ __launch_bounds__(256) void yolo_main(
        const float* __restrict__ outputs,   // (B, 125, 26, 26)
        const float* __restrict__ targets,   // (B, 50, 5)
        float* __restrict__ Lp, float* __restrict__ Mp, int* __restrict__ Anyp) {
    __shared__ float4 sbox[T];   // x1,y1,x2,y2 (degenerate if invalid)
    __shared__ float2 sas[T];    // area (1.0 if invalid), slot-as-int (-1 if invalid)
    __shared__ float4 stb[T];    // tb0..tb3
    __shared__ float  scls[T];
    __shared__ float  redl[4], redm[4];
    __shared__ int    reda[4];

    const int b   = blockIdx.y;
    const int tid = threadIdx.x;

    // ---- per-block GT decode ----
    if (tid < T) {
        const float* g = targets + ((size_t)b * T + tid) * 5;
        float rx1 = g[0], ry1 = g[1], rx2 = g[2], ry2 = g[3];
        bool valid = (rx1 + ry1 + rx2 + ry2) > 0.0f;
        float x1 = rx1 * FW, y1 = ry1 * FH, x2 = rx2 * FW, y2 = ry2 * FH;
        float w = x2 - x1, h = y2 - y1;

        float cxf = 0.5f * (x1 + x2), cyf = 0.5f * (y1 + y2);
        int cx = (int)floorf(cxf); cx = min(max(cx, 0), FW - 1);
        int cy = (int)floorf(cyf); cy = min(max(cy, 0), FH - 1);
        int cell = cy * FW + cx;

        // argmax over anchors (first max wins) of IoU(anchor@cell-center, gt)
        float acx = (float)cx + 0.5f, acy = (float)cy + 0.5f;
        float best = -1.0f; int ai = 0;
        for (int a = 0; a < A; ++a) {
            float aw = ANCW[a], ah = ANCH[a];
            float xi1 = fmaxf(acx - 0.5f * aw, x1), yi1 = fmaxf(acy - 0.5f * ah, y1);
            float xi2 = fminf(acx + 0.5f * aw, x2), yi2 = fminf(acy + 0.5f * ah, y2);
            float inter = fmaxf(xi2 - xi1, 0.0f) * fmaxf(yi2 - yi1, 0.0f);
            float iou = inter / (aw * ah + w * h - inter);
            if (iou > best) { best = iou; ai = a; }
        }

        if (valid) {
            sbox[tid] = make_float4(x1, y1, x2, y2);
            sas[tid]  = make_float2(w * h, __int_as_float(ai * K + cell));
        } else {
            sbox[tid] = make_float4(1e18f, 1e18f, -1e18f, -1e18f);  // inter -> 0
            sas[tid]  = make_float2(1.0f, __int_as_float(-1));       // iou -> 0
        }
        stb[tid]  = make_float4(cxf - (float)cx, cyf - (float)cy,
                                w / ANCW[ai], h / ANCH[ai]);
        scls[tid] = g[4];
    }
    __syncthreads();

    const int s = blockIdx.x * 256 + tid;
    float loss = 0.0f, masked = 0.0f;
    int any = 0;

    if (s < KA) {
        const int a = s / K, k = s - a * K;
        const int y = k / FW, x = k - y * FW;
        const float* ob = outputs + (size_t)b * CH * K;

        float o0 = ob[(a * 25 + 0) * K + k];
        float o1 = ob[(a * 25 + 1) * K + k];
        float o2 = ob[(a * 25 + 2) * K + k];
        float o3 = ob[(a * 25 + 3) * K + k];
        float o4 = ob[(a * 25 + 4) * K + k];

        float s0 = fast_sigmoid(o0), s1 = fast_sigmoid(o1);
        float e2 = __expf(o2),       e3 = __expf(o3);
        float px = (float)x + s0, py = (float)y + s1;
        float pw = ANCW[a] * e2,  ph = ANCH[a] * e3;
        float px1 = px - 0.5f * pw, px2 = px + 0.5f * pw;
        float py1 = py - 0.5f * ph, py2 = py + 0.5f * ph;
        float parea = pw * ph;

        float m = -1.0f;
        int w = -1;
        #pragma unroll 10
        for (int t = 0; t < T; ++t) {
            float4 bx  = sbox[t];
            float2 as2 = sas[t];
            float xi1 = fmaxf(px1, bx.x), yi1 = fmaxf(py1, bx.y);
            float xi2 = fminf(px2, bx.z), yi2 = fminf(py2, bx.w);
            float iw = fmaxf(xi2 - xi1, 0.0f), ih = fmaxf(yi2 - yi1, 0.0f);
            float inter = iw * ih;
            float iou = inter * __builtin_amdgcn_rcpf(parea + as2.x - inter);
            m = fmaxf(m, iou);
            if (__float_as_int(as2.y) == s) w = t;  // ascending t => last wins
        }
        any = (m > IGNORE_THRESH) ? 1 : 0;

        float conf = fast_sigmoid(o4);
        if (w >= 0) {
            // assigned: conf MSE at OBJ scale + box MSE + class CE
            float d = (conf - m) * OBJ_SCALE;
            loss += 0.5f * d * d;
            float4 tb = stb[w];
            float d0 = s0 - tb.x, d1 = s1 - tb.y;
            float d2 = e2 - tb.z, d3 = e3 - tb.w;
            loss += 0.5f * (d0 * d0 + d1 * d1 + d2 * d2 + d3 * d3);

            float v[NC];
            #pragma unroll
            for (int c = 0; c < NC; ++c) v[c] = ob[(a * 25 + 5 + c) * K + k];
            float mx = v[0];
            #pragma unroll
            for (int c = 1; c < NC; ++c) mx = fmaxf(mx, v[c]);
            float se = 0.0f;
            #pragma unroll
            for (int c = 0; c < NC; ++c) se += __expf(v[c] - mx);
            int cls = (int)scls[w];
            loss += (__logf(se) + mx) - v[cls];
        } else {
            // unassigned: noobj term (NOOBJ_SCALE=1); cancelled later if pos_any
            float term = 0.5f * conf * conf;
            loss += term;
            if (m >= IGNORE_THRESH) masked += term;
        }
    }

    // ---- block reduce ----
    for (int off = 32; off > 0; off >>= 1) {
        loss   += __shfl_down(loss, off);
        masked += __shfl_down(masked, off);
    }
    any = __any(any) ? 1 : 0;
    int lane = tid & 63, wv = tid >> 6;
    if (lane == 0) { redl[wv] = loss; redm[wv] = masked; reda[wv] = any; }
    __syncthreads();
    if (tid == 0) {
        int idx = b * CHUNKS + blockIdx.x;
        Lp[idx]   = redl[0] + redl[1] + redl[2] + redl[3];
        Mp[idx]   = redm[0] + redm[1] + redm[2] + redm[3];
        Anyp[idx] = reda[0] | reda[1] | reda[2] | reda[3];
    }
}

// ---------------------------------------------------------------------------
// Fix/reduce: thread b folds its 14 chunk-partials, applies the pos_any
// correction, block-reduces 128 values, single plain store of the scalar.
// ---------------------------------------------------------------------------
__global__ __launch_bounds__(128) void yolo_fix(
        const float* __restrict__ Lp, const float* __restrict__ Mp,
        const int* __restrict__ Anyp, float* __restrict__ out) {
    __shared__ float red[2];
    int tid = threadIdx.x;
    float L = 0.0f, M = 0.0f;
    int any = 0;
    if (tid < BN) {
        #pragma unroll
        for (int c = 0; c < CHUNKS; ++c) {
            int idx = tid * CHUNKS + c;
            L += Lp[idx];
            M += Mp[idx];
            any |= Anyp[idx];
        }
    }
    float acc = L - (any ? M : 0.0f);
    for (int off = 32; off > 0; off >>= 1) acc += __shfl_down(acc, off);
    if ((tid & 63) == 0) red[tid >> 6] = acc;
    __syncthreads();
    if (tid == 0) out[0] = (red[0] + red[1]) * (1.0f / (float)BN);
}

extern "C" void kernel_launch(void* const* d_in, const int* in_sizes, int n_in,
                              void* d_out, int out_size, void* d_ws, size_t ws_size,
                              hipStream_t stream) {
    const float* outputs = (const float*)d_in[0];
    const float* targets = (const float*)d_in[1];
    float* out = (float*)d_out;

    // ws layout: Lp[1792] | Mp[1792] | Anyp[1792]  (~21 KB, written before read)
    float* Lp   = (float*)d_ws;
    float* Mp   = Lp + NPART;
    int*   Anyp = (int*)(Mp + NPART);

    yolo_main<<<dim3(CHUNKS, BN), 256, 0, stream>>>(outputs, targets, Lp, Mp, Anyp);
    yolo_fix<<<1, 128, 0, stream>>>(Lp, Mp, Anyp, out);
}